// Round 1
// baseline (882.745 us; speedup 1.0000x reference)
//
#include <hip/hip_runtime.h>
#include <math.h>

// ---------------------------------------------------------------------------
// GCN diffusion forward on MI355X.
// Pipeline per call (all on `stream`, graph-capture safe):
//  1. zero deg/flag                          (N)
//  2. deg histogram over dst                 (E, int atomics)
//  3. label flags via atomicMax              (anm=1, norm=2; norm wins)
//  4. dinv = rsqrt(deg+1)
//  5. exclusive scan of deg -> rowstart (CSR), writepos = rowstart
//  6. CSR fill: col[slot]=src, srcdinv[slot]=dinv[src]
//  7. temb MLP (1 block)
//  8. x_t = noise_x + temb + label_emb[flag]
//  9. conv k: gemm (W in LDS) -> agg (wave per node, CSR gather) + bias + silu
// ---------------------------------------------------------------------------

__global__ __launch_bounds__(256) void zero_kernel(int* __restrict__ deg,
                                                   int* __restrict__ flag, int n) {
    int i = blockIdx.x * 256 + threadIdx.x;
    if (i < n) { deg[i] = 0; flag[i] = 0; }
}

__global__ __launch_bounds__(256) void count_deg_kernel(const int* __restrict__ ei,
                                                        int* __restrict__ deg, int e) {
    int i = blockIdx.x * 256 + threadIdx.x;
    if (i < e) atomicAdd(&deg[ei[e + i]], 1);   // dst row of edge_index
}

__global__ __launch_bounds__(256) void flags_kernel(const int* __restrict__ anm, int na,
                                                    const int* __restrict__ nrm, int nn,
                                                    int* __restrict__ flag) {
    int i = blockIdx.x * 256 + threadIdx.x;
    if (i < na) atomicMax(&flag[anm[i]], 1);
    if (i < nn) atomicMax(&flag[nrm[i]], 2);    // norm (2) overrides anm (1)
}

__global__ __launch_bounds__(256) void dinv_kernel(const int* __restrict__ deg,
                                                   float* __restrict__ dinv, int n) {
    int i = blockIdx.x * 256 + threadIdx.x;
    if (i < n) dinv[i] = rsqrtf((float)deg[i] + 1.0f);
}

// ---- exclusive scan of deg into rowstart (3-kernel, 1024 elems/block) ----
__global__ __launch_bounds__(256) void scan1_kernel(const int* __restrict__ deg,
                                                    int* __restrict__ rowstart,
                                                    int* __restrict__ blocksum, int n) {
    __shared__ int ts[256];
    int t = threadIdx.x;
    int base = blockIdx.x * 1024 + t * 4;
    int v0 = 0, v1 = 0, v2 = 0, v3 = 0;
    if (base + 0 < n) v0 = deg[base + 0];
    if (base + 1 < n) v1 = deg[base + 1];
    if (base + 2 < n) v2 = deg[base + 2];
    if (base + 3 < n) v3 = deg[base + 3];
    int s = v0 + v1 + v2 + v3;
    ts[t] = s;
    __syncthreads();
    for (int off = 1; off < 256; off <<= 1) {
        int add = (t >= off) ? ts[t - off] : 0;
        __syncthreads();
        ts[t] += add;
        __syncthreads();
    }
    if (t == 255) blocksum[blockIdx.x] = ts[255];
    int excl = ts[t] - s;
    if (base + 0 < n) rowstart[base + 0] = excl; excl += v0;
    if (base + 1 < n) rowstart[base + 1] = excl; excl += v1;
    if (base + 2 < n) rowstart[base + 2] = excl; excl += v2;
    if (base + 3 < n) rowstart[base + 3] = excl;
}

__global__ void scan2_kernel(int* __restrict__ blocksum, int nb) {
    if (threadIdx.x == 0 && blockIdx.x == 0) {
        int run = 0;
        for (int i = 0; i < nb; ++i) { int v = blocksum[i]; blocksum[i] = run; run += v; }
    }
}

__global__ __launch_bounds__(256) void scan3_kernel(int* __restrict__ rowstart,
                                                    const int* __restrict__ blocksum,
                                                    int* __restrict__ writepos, int n, int e) {
    int i = blockIdx.x * 256 + threadIdx.x;
    if (i < n) {
        int v = rowstart[i] + blocksum[i >> 10];
        rowstart[i] = v;
        writepos[i] = v;
    }
    if (i == 0) rowstart[n] = e;
}

__global__ __launch_bounds__(256) void fill_csr_kernel(const int* __restrict__ ei,
                                                       int* __restrict__ writepos,
                                                       int* __restrict__ col,
                                                       float* __restrict__ srcdinv,
                                                       const float* __restrict__ dinv, int e) {
    int i = blockIdx.x * 256 + threadIdx.x;
    if (i >= e) return;
    int src = ei[i];
    int dst = ei[e + i];
    int p = atomicAdd(&writepos[dst], 1);
    col[p] = src;
    srcdinv[p] = dinv[src];
}

// ---- time embedding MLP: [1,64] through two 64x64 layers with SiLU ----
__global__ void temb_kernel(const int* __restrict__ t,
                            const float* __restrict__ w1, const float* __restrict__ b1,
                            const float* __restrict__ w2, const float* __restrict__ b2,
                            float* __restrict__ temb) {
    __shared__ float emb[64], hid[64];
    int j = threadIdx.x;  // 64 threads
    float tf = (float)t[0];
    int h = j & 31;
    float freq = expf((float)h * -0.29710775393976190f);  // -ln(10000)/31
    float arg = tf * freq;
    emb[j] = (j < 32) ? sinf(arg) : cosf(arg);
    __syncthreads();
    float a = b1[j];
    for (int k = 0; k < 64; ++k) a = fmaf(emb[k], w1[k * 64 + j], a);
    hid[j] = a / (1.0f + expf(-a));  // SiLU
    __syncthreads();
    float o = b2[j];
    for (int k = 0; k < 64; ++k) o = fmaf(hid[k], w2[k * 64 + j], o);
    temb[j] = o;
}

// ---- x_t = noise_x + temb + label_emb[flag], float4 vectorized ----
__global__ __launch_bounds__(256) void xt_kernel(const float* __restrict__ nx,
                                                 const float* __restrict__ temb,
                                                 const float* __restrict__ lemb,
                                                 const int* __restrict__ flag,
                                                 float* __restrict__ xt, int n) {
    int t = blockIdx.x * 256 + threadIdx.x;
    int total = n * 16;
    if (t >= total) return;
    int row = t >> 4;
    int c4 = (t & 15) * 4;
    float4 v = *(const float4*)(nx + (size_t)row * 64 + c4);
    float4 tv = *(const float4*)(temb + c4);
    v.x += tv.x; v.y += tv.y; v.z += tv.z; v.w += tv.w;
    int f = flag[row];
    if (f) {
        const float* le = lemb + (f == 1 ? 64 : 0);  // 1->label_emb[1], 2->label_emb[0]
        float4 lv = *(const float4*)(le + c4);
        v.x += lv.x; v.y += lv.y; v.z += lv.z; v.w += lv.w;
    }
    *(float4*)(xt + (size_t)row * 64 + c4) = v;
}

// ---- dense x[N,K] @ w[K,M] -> y[N,M]; W in LDS; 2 rows x 32 cols / thread ----
template <int K, int M, bool ACCUM>
__global__ __launch_bounds__(256) void gemm_kernel(const float* __restrict__ x,
                                                   const float* __restrict__ w,
                                                   float* __restrict__ y, int n) {
    constexpr int PARTS = M / 32;
    __shared__ float wl[K * M];
    for (int i = threadIdx.x; i < K * M; i += 256) wl[i] = w[i];
    __syncthreads();
    long g = (long)blockIdx.x * 256 + threadIdx.x;
    int pair = (int)(g / PARTS);
    int part = (int)(g % PARTS);
    int r0 = pair * 2, r1 = r0 + 1;
    if (r0 >= n) return;
    bool has1 = (r1 < n);
    float a0[32], a1[32];
#pragma unroll
    for (int m = 0; m < 32; ++m) { a0[m] = 0.f; a1[m] = 0.f; }
    const float* x0 = x + (size_t)r0 * K;
    const float* x1 = x + (size_t)r1 * K;
#pragma unroll 4
    for (int k = 0; k < K; ++k) {
        float xk0 = x0[k];
        float xk1 = has1 ? x1[k] : 0.f;
        const float* wr = wl + k * M + part * 32;
#pragma unroll
        for (int m = 0; m < 32; ++m) {
            float wv = wr[m];
            a0[m] = fmaf(xk0, wv, a0[m]);
            a1[m] = fmaf(xk1, wv, a1[m]);
        }
    }
    float* y0 = y + (size_t)r0 * M + part * 32;
#pragma unroll
    for (int m = 0; m < 32; ++m) y0[m] = ACCUM ? y0[m] + a0[m] : a0[m];
    if (has1) {
        float* y1 = y + (size_t)r1 * M + part * 32;
#pragma unroll
        for (int m = 0; m < 32; ++m) y1[m] = ACCUM ? y1[m] + a1[m] : a1[m];
    }
}

// ---- aggregation: one wave per dst node; CSR gather; + self loop, bias, SiLU ----
template <int D>
__global__ __launch_bounds__(256) void agg_kernel(const float* __restrict__ xw,
                                                  const int* __restrict__ rowstart,
                                                  const int* __restrict__ col,
                                                  const float* __restrict__ srcdinv,
                                                  const float* __restrict__ dinv,
                                                  const float* __restrict__ bias,
                                                  float* __restrict__ y, int n) {
    int wid = (int)(((size_t)blockIdx.x * blockDim.x + threadIdx.x) >> 6);
    int lane = threadIdx.x & 63;
    if (wid >= n) return;
    float di = dinv[wid];
    int s = rowstart[wid], e1 = rowstart[wid + 1];
    if (D == 128) {
        const float2* xv = (const float2*)xw;
        float2 acc = make_float2(0.f, 0.f);
        for (int e = s; e < e1; ++e) {
            int src = col[e];
            float w = srcdinv[e] * di;
            float2 v = xv[(size_t)src * 64 + lane];
            acc.x = fmaf(v.x, w, acc.x);
            acc.y = fmaf(v.y, w, acc.y);
        }
        float sw = di * di;
        float2 sv = xv[(size_t)wid * 64 + lane];
        acc.x = fmaf(sv.x, sw, acc.x) + bias[lane * 2];
        acc.y = fmaf(sv.y, sw, acc.y) + bias[lane * 2 + 1];
        acc.x = acc.x / (1.0f + expf(-acc.x));
        acc.y = acc.y / (1.0f + expf(-acc.y));
        ((float2*)y)[(size_t)wid * 64 + lane] = acc;
    } else {
        float acc = 0.f;
        for (int e = s; e < e1; ++e) {
            int src = col[e];
            float w = srcdinv[e] * di;
            acc = fmaf(xw[(size_t)src * 64 + lane], w, acc);
        }
        float sw = di * di;
        acc = fmaf(xw[(size_t)wid * 64 + lane], sw, acc) + bias[lane];
        acc = acc / (1.0f + expf(-acc));
        y[(size_t)wid * 64 + lane] = acc;
    }
}

static inline int gemm_grid(int n, int parts) {
    long pairs = (n + 1) / 2;
    long threads = pairs * parts;
    return (int)((threads + 255) / 256);
}

extern "C" void kernel_launch(void* const* d_in, const int* in_sizes, int n_in,
                              void* d_out, int out_size, void* d_ws, size_t ws_size,
                              hipStream_t stream) {
    const float* noise_x = (const float*)d_in[0];
    const int*   edge    = (const int*)d_in[1];
    const int*   tptr    = (const int*)d_in[2];
    const int*   anm     = (const int*)d_in[3];
    const int*   nrm     = (const int*)d_in[4];
    const float* tw1     = (const float*)d_in[5];
    const float* tb1     = (const float*)d_in[6];
    const float* tw2     = (const float*)d_in[7];
    const float* tb2     = (const float*)d_in[8];
    const float* lemb    = (const float*)d_in[9];
    const float* w0      = (const float*)d_in[10];
    const float* b0      = (const float*)d_in[11];
    const float* w1      = (const float*)d_in[12];
    const float* b1      = (const float*)d_in[13];
    const float* w2      = (const float*)d_in[14];
    const float* b2      = (const float*)d_in[15];
    const float* w3      = (const float*)d_in[16];
    const float* b3      = (const float*)d_in[17];

    const int N = in_sizes[0] / 64;
    const int E = in_sizes[1] / 2;
    const int na = in_sizes[3];
    const int nn = in_sizes[4];
    float* out = (float*)d_out;

    // workspace carve-out (256B aligned)
    char* ws = (char*)d_ws;
    size_t o = 0;
    auto carve = [&](size_t bytes) -> char* {
        char* p = ws + o;
        o += (bytes + 255) & ~(size_t)255;
        return p;
    };
    int*   deg      = (int*)carve((size_t)N * 4);
    int*   flag     = (int*)carve((size_t)N * 4);
    int*   rowstart = (int*)carve((size_t)(N + 1) * 4);
    int*   writepos = (int*)carve((size_t)N * 4);
    int*   blocksum = (int*)carve(4096);
    int*   col      = (int*)carve((size_t)E * 4);
    float* srcdinv  = (float*)carve((size_t)E * 4);
    float* dinv     = (float*)carve((size_t)N * 4);
    float* temb     = (float*)carve(256);
    float* bufX     = (float*)carve((size_t)N * 64 * 4);   // x_t -> xw1 -> xw3
    float* bufA     = (float*)carve((size_t)N * 128 * 4);  // xw0 -> h1 -> h2
    float* bufB     = (float*)carve((size_t)N * 128 * 4);  // h0 (live to end)
    float* bufC     = (float*)carve((size_t)N * 128 * 4);  // xw2

    const int nblkN = (N + 255) / 256;
    const int nblkE = (E + 255) / 256;
    const int nb = (N + 1023) / 1024;
    const int nmax = na > nn ? na : nn;

    zero_kernel<<<nblkN, 256, 0, stream>>>(deg, flag, N);
    count_deg_kernel<<<nblkE, 256, 0, stream>>>(edge, deg, E);
    flags_kernel<<<(nmax + 255) / 256, 256, 0, stream>>>(anm, na, nrm, nn, flag);
    dinv_kernel<<<nblkN, 256, 0, stream>>>(deg, dinv, N);
    scan1_kernel<<<nb, 256, 0, stream>>>(deg, rowstart, blocksum, N);
    scan2_kernel<<<1, 64, 0, stream>>>(blocksum, nb);
    scan3_kernel<<<nblkN, 256, 0, stream>>>(rowstart, blocksum, writepos, N, E);
    fill_csr_kernel<<<nblkE, 256, 0, stream>>>(edge, writepos, col, srcdinv, dinv, E);
    temb_kernel<<<1, 64, 0, stream>>>(tptr, tw1, tb1, tw2, tb2, temb);
    xt_kernel<<<((size_t)N * 16 + 255) / 256, 256, 0, stream>>>(noise_x, temb, lemb, flag, bufX, N);

    // conv0: x_t[64] -> 128
    gemm_kernel<64, 128, false><<<gemm_grid(N, 4), 256, 0, stream>>>(bufX, w0, bufA, N);
    agg_kernel<128><<<(N + 3) / 4, 256, 0, stream>>>(bufA, rowstart, col, srcdinv, dinv, b0, bufB, N);
    // conv1: h0[128] -> 64
    gemm_kernel<128, 64, false><<<gemm_grid(N, 2), 256, 0, stream>>>(bufB, w1, bufX, N);
    agg_kernel<64><<<(N + 3) / 4, 256, 0, stream>>>(bufX, rowstart, col, srcdinv, dinv, b1, bufA, N);
    // conv2: h1[64] -> 128
    gemm_kernel<64, 128, false><<<gemm_grid(N, 4), 256, 0, stream>>>(bufA, w2, bufC, N);
    agg_kernel<128><<<(N + 3) / 4, 256, 0, stream>>>(bufC, rowstart, col, srcdinv, dinv, b2, bufA, N);
    // conv3: concat(h2,h0)[256] -> 64  == h2 @ w3[0:128] + h0 @ w3[128:256]
    gemm_kernel<128, 64, false><<<gemm_grid(N, 2), 256, 0, stream>>>(bufA, w3, bufX, N);
    gemm_kernel<128, 64, true><<<gemm_grid(N, 2), 256, 0, stream>>>(bufB, w3 + 128 * 64, bufX, N);
    agg_kernel<64><<<(N + 3) / 4, 256, 0, stream>>>(bufX, rowstart, col, srcdinv, dinv, b3, out, N);
}

// Round 2
// 667.313 us; speedup vs baseline: 1.3228x; 1.3228x over previous
//
#include <hip/hip_runtime.h>
#include <math.h>

// ---------------------------------------------------------------------------
// GCN diffusion forward on MI355X — round 2.
// Key change vs R1: aggregation is linear, so agg(xW) == agg(x)W. Every conv
// now gathers the 64-dim side:
//   conv0: aggX=agg(x_t)[64] -> gemm 64->128 (+b0,silu) -> h0
//   conv1: xw1=h0@w1[64]     -> agg (+b1,silu)          -> h1
//   conv2: aggH1=agg(h1)[64] -> gemm 64->128 (+b2,silu) -> h2
//   conv3: z=h2@w3a+h0@w3b   -> agg (+b3,silu)          -> out  (fused cat gemm)
// CSR payload packed as int2(col, bits(dinv[src])); agg unrolled x4 with 4
// independent accumulators (latency-bound random gather).
// ---------------------------------------------------------------------------

__global__ __launch_bounds__(256) void zero_kernel(int* __restrict__ deg,
                                                   int* __restrict__ flag, int n) {
    int i = blockIdx.x * 256 + threadIdx.x;
    if (i < n) { deg[i] = 0; flag[i] = 0; }
}

__global__ __launch_bounds__(256) void count_deg_kernel(const int* __restrict__ ei,
                                                        int* __restrict__ deg, int e) {
    int i = blockIdx.x * 256 + threadIdx.x;
    if (i < e) atomicAdd(&deg[ei[e + i]], 1);   // dst row of edge_index
}

__global__ __launch_bounds__(256) void flags_kernel(const int* __restrict__ anm, int na,
                                                    const int* __restrict__ nrm, int nn,
                                                    int* __restrict__ flag) {
    int i = blockIdx.x * 256 + threadIdx.x;
    if (i < na) atomicMax(&flag[anm[i]], 1);
    if (i < nn) atomicMax(&flag[nrm[i]], 2);    // norm (2) overrides anm (1)
}

__global__ __launch_bounds__(256) void dinv_kernel(const int* __restrict__ deg,
                                                   float* __restrict__ dinv, int n) {
    int i = blockIdx.x * 256 + threadIdx.x;
    if (i < n) dinv[i] = rsqrtf((float)deg[i] + 1.0f);
}

// ---- exclusive scan of deg into rowstart (3-kernel, 1024 elems/block) ----
__global__ __launch_bounds__(256) void scan1_kernel(const int* __restrict__ deg,
                                                    int* __restrict__ rowstart,
                                                    int* __restrict__ blocksum, int n) {
    __shared__ int ts[256];
    int t = threadIdx.x;
    int base = blockIdx.x * 1024 + t * 4;
    int v0 = 0, v1 = 0, v2 = 0, v3 = 0;
    if (base + 0 < n) v0 = deg[base + 0];
    if (base + 1 < n) v1 = deg[base + 1];
    if (base + 2 < n) v2 = deg[base + 2];
    if (base + 3 < n) v3 = deg[base + 3];
    int s = v0 + v1 + v2 + v3;
    ts[t] = s;
    __syncthreads();
    for (int off = 1; off < 256; off <<= 1) {
        int add = (t >= off) ? ts[t - off] : 0;
        __syncthreads();
        ts[t] += add;
        __syncthreads();
    }
    if (t == 255) blocksum[blockIdx.x] = ts[255];
    int excl = ts[t] - s;
    if (base + 0 < n) rowstart[base + 0] = excl; excl += v0;
    if (base + 1 < n) rowstart[base + 1] = excl; excl += v1;
    if (base + 2 < n) rowstart[base + 2] = excl; excl += v2;
    if (base + 3 < n) rowstart[base + 3] = excl;
}

__global__ void scan2_kernel(int* __restrict__ blocksum, int nb) {
    if (threadIdx.x == 0 && blockIdx.x == 0) {
        int run = 0;
        for (int i = 0; i < nb; ++i) { int v = blocksum[i]; blocksum[i] = run; run += v; }
    }
}

__global__ __launch_bounds__(256) void scan3_kernel(int* __restrict__ rowstart,
                                                    const int* __restrict__ blocksum,
                                                    int* __restrict__ writepos, int n, int e) {
    int i = blockIdx.x * 256 + threadIdx.x;
    if (i < n) {
        int v = rowstart[i] + blocksum[i >> 10];
        rowstart[i] = v;
        writepos[i] = v;
    }
    if (i == 0) rowstart[n] = e;
}

// CSR fill: one 8B scattered write per edge: (src, bits(dinv[src]))
__global__ __launch_bounds__(256) void fill_csr_kernel(const int* __restrict__ ei,
                                                       int* __restrict__ writepos,
                                                       int2* __restrict__ cs,
                                                       const float* __restrict__ dinv, int e) {
    int i = blockIdx.x * 256 + threadIdx.x;
    if (i >= e) return;
    int src = ei[i];
    int dst = ei[e + i];
    int p = atomicAdd(&writepos[dst], 1);
    cs[p] = make_int2(src, __float_as_int(dinv[src]));
}

// ---- time embedding MLP: [1,64] through two 64x64 layers with SiLU ----
__global__ void temb_kernel(const int* __restrict__ t,
                            const float* __restrict__ w1, const float* __restrict__ b1,
                            const float* __restrict__ w2, const float* __restrict__ b2,
                            float* __restrict__ temb) {
    __shared__ float emb[64], hid[64];
    int j = threadIdx.x;  // 64 threads
    float tf = (float)t[0];
    int h = j & 31;
    float freq = expf((float)h * -0.29710775393976190f);  // -ln(10000)/31
    float arg = tf * freq;
    emb[j] = (j < 32) ? sinf(arg) : cosf(arg);
    __syncthreads();
    float a = b1[j];
    for (int k = 0; k < 64; ++k) a = fmaf(emb[k], w1[k * 64 + j], a);
    hid[j] = a / (1.0f + expf(-a));  // SiLU
    __syncthreads();
    float o = b2[j];
    for (int k = 0; k < 64; ++k) o = fmaf(hid[k], w2[k * 64 + j], o);
    temb[j] = o;
}

// ---- x_t = noise_x + temb + label_emb[flag], float4 vectorized ----
__global__ __launch_bounds__(256) void xt_kernel(const float* __restrict__ nx,
                                                 const float* __restrict__ temb,
                                                 const float* __restrict__ lemb,
                                                 const int* __restrict__ flag,
                                                 float* __restrict__ xt, int n) {
    int t = blockIdx.x * 256 + threadIdx.x;
    int total = n * 16;
    if (t >= total) return;
    int row = t >> 4;
    int c4 = (t & 15) * 4;
    float4 v = *(const float4*)(nx + (size_t)row * 64 + c4);
    float4 tv = *(const float4*)(temb + c4);
    v.x += tv.x; v.y += tv.y; v.z += tv.z; v.w += tv.w;
    int f = flag[row];
    if (f) {
        const float* le = lemb + (f == 1 ? 64 : 0);  // 1->label_emb[1], 2->label_emb[0]
        float4 lv = *(const float4*)(le + c4);
        v.x += lv.x; v.y += lv.y; v.z += lv.z; v.w += lv.w;
    }
    *(float4*)(xt + (size_t)row * 64 + c4) = v;
}

// ---- aggregation over 64-dim rows: one wave per node, unroll x4 ----
template <bool BIAS_SILU>
__global__ __launch_bounds__(256) void agg64_kernel(const float* __restrict__ xw,
                                                    const int* __restrict__ rowstart,
                                                    const int2* __restrict__ cs,
                                                    const float* __restrict__ dinv,
                                                    const float* __restrict__ bias,
                                                    float* __restrict__ y, int n) {
    int wid = (int)(((size_t)blockIdx.x * 256 + threadIdx.x) >> 6);
    int lane = threadIdx.x & 63;
    if (wid >= n) return;
    float di = dinv[wid];
    int s = rowstart[wid], e1 = rowstart[wid + 1];
    float a0 = 0.f, a1 = 0.f, a2 = 0.f, a3 = 0.f;
    int e = s;
    for (; e + 4 <= e1; e += 4) {
        int2 c0 = cs[e], c1 = cs[e + 1], c2 = cs[e + 2], c3 = cs[e + 3];
        float v0 = xw[(size_t)c0.x * 64 + lane];
        float v1 = xw[(size_t)c1.x * 64 + lane];
        float v2 = xw[(size_t)c2.x * 64 + lane];
        float v3 = xw[(size_t)c3.x * 64 + lane];
        a0 = fmaf(v0, __int_as_float(c0.y) * di, a0);
        a1 = fmaf(v1, __int_as_float(c1.y) * di, a1);
        a2 = fmaf(v2, __int_as_float(c2.y) * di, a2);
        a3 = fmaf(v3, __int_as_float(c3.y) * di, a3);
    }
    for (; e < e1; ++e) {
        int2 c = cs[e];
        a0 = fmaf(xw[(size_t)c.x * 64 + lane], __int_as_float(c.y) * di, a0);
    }
    float acc = (a0 + a1) + (a2 + a3);
    acc = fmaf(xw[(size_t)wid * 64 + lane], di * di, acc);
    if (BIAS_SILU) {
        acc += bias[lane];
        acc = acc / (1.0f + expf(-acc));
    }
    y[(size_t)wid * 64 + lane] = acc;
}

// ---- dense x[N,K] @ w[K,M] -> y[N,M]; W in LDS; 2 rows x 32 cols / thread ----
// MODE: 0 = plain, 1 = +bias +SiLU
template <int K, int M, int MODE>
__global__ __launch_bounds__(256) void gemm_kernel(const float* __restrict__ x,
                                                   const float* __restrict__ w,
                                                   const float* __restrict__ bias,
                                                   float* __restrict__ y, int n) {
    constexpr int PARTS = M / 32;
    __shared__ float wl[K * M];
    for (int i = threadIdx.x; i < K * M; i += 256) wl[i] = w[i];
    __syncthreads();
    long g = (long)blockIdx.x * 256 + threadIdx.x;
    int pair = (int)(g / PARTS);
    int part = (int)(g % PARTS);
    int r0 = pair * 2, r1 = r0 + 1;
    if (r0 >= n) return;
    bool has1 = (r1 < n);
    float a0[32], a1[32];
#pragma unroll
    for (int m = 0; m < 32; ++m) { a0[m] = 0.f; a1[m] = 0.f; }
    const float* x0 = x + (size_t)r0 * K;
    const float* x1 = x + (size_t)r1 * K;
#pragma unroll 4
    for (int k = 0; k < K; ++k) {
        float xk0 = x0[k];
        float xk1 = has1 ? x1[k] : 0.f;
        const float* wr = wl + k * M + part * 32;
#pragma unroll
        for (int m = 0; m < 32; ++m) {
            float wv = wr[m];
            a0[m] = fmaf(xk0, wv, a0[m]);
            a1[m] = fmaf(xk1, wv, a1[m]);
        }
    }
    const float* bp = bias + part * 32;
    float* y0 = y + (size_t)r0 * M + part * 32;
#pragma unroll
    for (int m = 0; m < 32; ++m) {
        float v = a0[m];
        if (MODE == 1) { v += bp[m]; v = v / (1.0f + expf(-v)); }
        y0[m] = v;
    }
    if (has1) {
        float* y1 = y + (size_t)r1 * M + part * 32;
#pragma unroll
        for (int m = 0; m < 32; ++m) {
            float v = a1[m];
            if (MODE == 1) { v += bp[m]; v = v / (1.0f + expf(-v)); }
            y1[m] = v;
        }
    }
}

// ---- y = xa @ w[0:K,:] + xb @ w[K:2K,:]  (concat gemm, two LDS passes) ----
template <int K, int M>
__global__ __launch_bounds__(256) void gemm_cat_kernel(const float* __restrict__ xa,
                                                       const float* __restrict__ xb,
                                                       const float* __restrict__ w,
                                                       float* __restrict__ y, int n) {
    constexpr int PARTS = M / 32;
    __shared__ float wl[K * M];
    long g = (long)blockIdx.x * 256 + threadIdx.x;
    int pair = (int)(g / PARTS);
    int part = (int)(g % PARTS);
    int r0 = pair * 2, r1 = r0 + 1;
    bool active = (r0 < n);
    bool has1 = (r1 < n);
    float a0[32], a1[32];
#pragma unroll
    for (int m = 0; m < 32; ++m) { a0[m] = 0.f; a1[m] = 0.f; }

    for (int half = 0; half < 2; ++half) {
        __syncthreads();
        for (int i = threadIdx.x; i < K * M; i += 256) wl[i] = w[half * K * M + i];
        __syncthreads();
        if (active) {
            const float* xs = half ? xb : xa;
            const float* x0 = xs + (size_t)r0 * K;
            const float* x1 = xs + (size_t)r1 * K;
#pragma unroll 4
            for (int k = 0; k < K; ++k) {
                float xk0 = x0[k];
                float xk1 = has1 ? x1[k] : 0.f;
                const float* wr = wl + k * M + part * 32;
#pragma unroll
                for (int m = 0; m < 32; ++m) {
                    float wv = wr[m];
                    a0[m] = fmaf(xk0, wv, a0[m]);
                    a1[m] = fmaf(xk1, wv, a1[m]);
                }
            }
        }
    }
    if (!active) return;
    float* y0 = y + (size_t)r0 * M + part * 32;
#pragma unroll
    for (int m = 0; m < 32; ++m) y0[m] = a0[m];
    if (has1) {
        float* y1 = y + (size_t)r1 * M + part * 32;
#pragma unroll
        for (int m = 0; m < 32; ++m) y1[m] = a1[m];
    }
}

static inline int gemm_grid(int n, int parts) {
    long pairs = (n + 1) / 2;
    long threads = pairs * parts;
    return (int)((threads + 255) / 256);
}

extern "C" void kernel_launch(void* const* d_in, const int* in_sizes, int n_in,
                              void* d_out, int out_size, void* d_ws, size_t ws_size,
                              hipStream_t stream) {
    const float* noise_x = (const float*)d_in[0];
    const int*   edge    = (const int*)d_in[1];
    const int*   tptr    = (const int*)d_in[2];
    const int*   anm     = (const int*)d_in[3];
    const int*   nrm     = (const int*)d_in[4];
    const float* tw1     = (const float*)d_in[5];
    const float* tb1     = (const float*)d_in[6];
    const float* tw2     = (const float*)d_in[7];
    const float* tb2     = (const float*)d_in[8];
    const float* lemb    = (const float*)d_in[9];
    const float* w0      = (const float*)d_in[10];
    const float* b0      = (const float*)d_in[11];
    const float* w1      = (const float*)d_in[12];
    const float* b1      = (const float*)d_in[13];
    const float* w2      = (const float*)d_in[14];
    const float* b2      = (const float*)d_in[15];
    const float* w3      = (const float*)d_in[16];
    const float* b3      = (const float*)d_in[17];

    const int N = in_sizes[0] / 64;
    const int E = in_sizes[1] / 2;
    const int na = in_sizes[3];
    const int nn = in_sizes[4];
    float* out = (float*)d_out;

    // workspace carve-out (256B aligned)
    char* ws = (char*)d_ws;
    size_t o = 0;
    auto carve = [&](size_t bytes) -> char* {
        char* p = ws + o;
        o += (bytes + 255) & ~(size_t)255;
        return p;
    };
    int*   deg      = (int*)carve((size_t)N * 4);
    int*   flag     = (int*)carve((size_t)N * 4);
    int*   rowstart = (int*)carve((size_t)(N + 1) * 4);
    int*   writepos = (int*)carve((size_t)N * 4);
    int*   blocksum = (int*)carve(4096);
    int2*  cs       = (int2*)carve((size_t)E * 8);
    float* dinv     = (float*)carve((size_t)N * 4);
    float* temb     = (float*)carve(256);
    float* bufP     = (float*)carve((size_t)N * 64 * 4);   // x_t -> xw1 -> aggH1 -> z3
    float* bufQ     = (float*)carve((size_t)N * 64 * 4);   // aggX -> h1
    float* bufR     = (float*)carve((size_t)N * 128 * 4);  // h0 (live to end)
    float* bufS     = (float*)carve((size_t)N * 128 * 4);  // h2

    const int nblkN = (N + 255) / 256;
    const int nblkE = (E + 255) / 256;
    const int nb = (N + 1023) / 1024;
    const int nmax = na > nn ? na : nn;
    const int aggBlk = (N + 3) / 4;   // 4 waves (nodes) per 256-thread block

    zero_kernel<<<nblkN, 256, 0, stream>>>(deg, flag, N);
    count_deg_kernel<<<nblkE, 256, 0, stream>>>(edge, deg, E);
    flags_kernel<<<(nmax + 255) / 256, 256, 0, stream>>>(anm, na, nrm, nn, flag);
    dinv_kernel<<<nblkN, 256, 0, stream>>>(deg, dinv, N);
    scan1_kernel<<<nb, 256, 0, stream>>>(deg, rowstart, blocksum, N);
    scan2_kernel<<<1, 64, 0, stream>>>(blocksum, nb);
    scan3_kernel<<<nblkN, 256, 0, stream>>>(rowstart, blocksum, writepos, N, E);
    fill_csr_kernel<<<nblkE, 256, 0, stream>>>(edge, writepos, cs, dinv, E);
    temb_kernel<<<1, 64, 0, stream>>>(tptr, tw1, tb1, tw2, tb2, temb);
    xt_kernel<<<((size_t)N * 16 + 255) / 256, 256, 0, stream>>>(noise_x, temb, lemb, flag, bufP, N);

    // conv0: aggX = agg(x_t); h0 = silu(aggX @ w0 + b0)
    agg64_kernel<false><<<aggBlk, 256, 0, stream>>>(bufP, rowstart, cs, dinv, nullptr, bufQ, N);
    gemm_kernel<64, 128, 1><<<gemm_grid(N, 4), 256, 0, stream>>>(bufQ, w0, b0, bufR, N);
    // conv1: xw1 = h0 @ w1; h1 = silu(agg(xw1) + b1)
    gemm_kernel<128, 64, 0><<<gemm_grid(N, 2), 256, 0, stream>>>(bufR, w1, nullptr, bufP, N);
    agg64_kernel<true><<<aggBlk, 256, 0, stream>>>(bufP, rowstart, cs, dinv, b1, bufQ, N);
    // conv2: aggH1 = agg(h1); h2 = silu(aggH1 @ w2 + b2)
    agg64_kernel<false><<<aggBlk, 256, 0, stream>>>(bufQ, rowstart, cs, dinv, nullptr, bufP, N);
    gemm_kernel<64, 128, 1><<<gemm_grid(N, 4), 256, 0, stream>>>(bufP, w2, b2, bufS, N);
    // conv3: z3 = h2 @ w3[0:128] + h0 @ w3[128:256]; out = silu(agg(z3) + b3)
    gemm_cat_kernel<128, 64><<<gemm_grid(N, 2), 256, 0, stream>>>(bufS, bufR, w3, bufP, N);
    agg64_kernel<true><<<aggBlk, 256, 0, stream>>>(bufP, rowstart, cs, dinv, b3, out, N);
}

// Round 3
// 554.766 us; speedup vs baseline: 1.5912x; 1.2029x over previous
//
#include <hip/hip_runtime.h>
#include <math.h>

// ---------------------------------------------------------------------------
// GCN diffusion forward on MI355X — round 3.
// vs R2: GEMMs restructured as LDS-tiled (128-row x M tile per 256-thread
// block, X and W staged in LDS, 4 rows x M/8 cols per thread, K in 64-wide
// quarters). Fixes the R2 gemm pathology (391 blocks, scalar x loads,
// VALUBusy 17%). agg64 unrolled x8. All f32.
// ---------------------------------------------------------------------------

__global__ __launch_bounds__(256) void zero_kernel(int* __restrict__ deg,
                                                   int* __restrict__ flag, int n) {
    int i = blockIdx.x * 256 + threadIdx.x;
    if (i < n) { deg[i] = 0; flag[i] = 0; }
}

__global__ __launch_bounds__(256) void count_deg_kernel(const int* __restrict__ ei,
                                                        int* __restrict__ deg, int e) {
    int i = blockIdx.x * 256 + threadIdx.x;
    if (i < e) atomicAdd(&deg[ei[e + i]], 1);   // dst row of edge_index
}

__global__ __launch_bounds__(256) void flags_kernel(const int* __restrict__ anm, int na,
                                                    const int* __restrict__ nrm, int nn,
                                                    int* __restrict__ flag) {
    int i = blockIdx.x * 256 + threadIdx.x;
    if (i < na) atomicMax(&flag[anm[i]], 1);
    if (i < nn) atomicMax(&flag[nrm[i]], 2);    // norm (2) overrides anm (1)
}

__global__ __launch_bounds__(256) void dinv_kernel(const int* __restrict__ deg,
                                                   float* __restrict__ dinv, int n) {
    int i = blockIdx.x * 256 + threadIdx.x;
    if (i < n) dinv[i] = rsqrtf((float)deg[i] + 1.0f);
}

// ---- exclusive scan of deg into rowstart (3-kernel, 1024 elems/block) ----
__global__ __launch_bounds__(256) void scan1_kernel(const int* __restrict__ deg,
                                                    int* __restrict__ rowstart,
                                                    int* __restrict__ blocksum, int n) {
    __shared__ int ts[256];
    int t = threadIdx.x;
    int base = blockIdx.x * 1024 + t * 4;
    int v0 = 0, v1 = 0, v2 = 0, v3 = 0;
    if (base + 0 < n) v0 = deg[base + 0];
    if (base + 1 < n) v1 = deg[base + 1];
    if (base + 2 < n) v2 = deg[base + 2];
    if (base + 3 < n) v3 = deg[base + 3];
    int s = v0 + v1 + v2 + v3;
    ts[t] = s;
    __syncthreads();
    for (int off = 1; off < 256; off <<= 1) {
        int add = (t >= off) ? ts[t - off] : 0;
        __syncthreads();
        ts[t] += add;
        __syncthreads();
    }
    if (t == 255) blocksum[blockIdx.x] = ts[255];
    int excl = ts[t] - s;
    if (base + 0 < n) rowstart[base + 0] = excl; excl += v0;
    if (base + 1 < n) rowstart[base + 1] = excl; excl += v1;
    if (base + 2 < n) rowstart[base + 2] = excl; excl += v2;
    if (base + 3 < n) rowstart[base + 3] = excl;
}

__global__ void scan2_kernel(int* __restrict__ blocksum, int nb) {
    if (threadIdx.x == 0 && blockIdx.x == 0) {
        int run = 0;
        for (int i = 0; i < nb; ++i) { int v = blocksum[i]; blocksum[i] = run; run += v; }
    }
}

__global__ __launch_bounds__(256) void scan3_kernel(int* __restrict__ rowstart,
                                                    const int* __restrict__ blocksum,
                                                    int* __restrict__ writepos, int n, int e) {
    int i = blockIdx.x * 256 + threadIdx.x;
    if (i < n) {
        int v = rowstart[i] + blocksum[i >> 10];
        rowstart[i] = v;
        writepos[i] = v;
    }
    if (i == 0) rowstart[n] = e;
}

// CSR fill: one 8B scattered write per edge: (src, bits(dinv[src]))
__global__ __launch_bounds__(256) void fill_csr_kernel(const int* __restrict__ ei,
                                                       int* __restrict__ writepos,
                                                       int2* __restrict__ cs,
                                                       const float* __restrict__ dinv, int e) {
    int i = blockIdx.x * 256 + threadIdx.x;
    if (i >= e) return;
    int src = ei[i];
    int dst = ei[e + i];
    int p = atomicAdd(&writepos[dst], 1);
    cs[p] = make_int2(src, __float_as_int(dinv[src]));
}

// ---- time embedding MLP: [1,64] through two 64x64 layers with SiLU ----
__global__ void temb_kernel(const int* __restrict__ t,
                            const float* __restrict__ w1, const float* __restrict__ b1,
                            const float* __restrict__ w2, const float* __restrict__ b2,
                            float* __restrict__ temb) {
    __shared__ float emb[64], hid[64];
    int j = threadIdx.x;  // 64 threads
    float tf = (float)t[0];
    int h = j & 31;
    float freq = expf((float)h * -0.29710775393976190f);  // -ln(10000)/31
    float arg = tf * freq;
    emb[j] = (j < 32) ? sinf(arg) : cosf(arg);
    __syncthreads();
    float a = b1[j];
    for (int k = 0; k < 64; ++k) a = fmaf(emb[k], w1[k * 64 + j], a);
    hid[j] = a / (1.0f + expf(-a));  // SiLU
    __syncthreads();
    float o = b2[j];
    for (int k = 0; k < 64; ++k) o = fmaf(hid[k], w2[k * 64 + j], o);
    temb[j] = o;
}

// ---- x_t = noise_x + temb + label_emb[flag], float4 vectorized ----
__global__ __launch_bounds__(256) void xt_kernel(const float* __restrict__ nx,
                                                 const float* __restrict__ temb,
                                                 const float* __restrict__ lemb,
                                                 const int* __restrict__ flag,
                                                 float* __restrict__ xt, int n) {
    int t = blockIdx.x * 256 + threadIdx.x;
    int total = n * 16;
    if (t >= total) return;
    int row = t >> 4;
    int c4 = (t & 15) * 4;
    float4 v = *(const float4*)(nx + (size_t)row * 64 + c4);
    float4 tv = *(const float4*)(temb + c4);
    v.x += tv.x; v.y += tv.y; v.z += tv.z; v.w += tv.w;
    int f = flag[row];
    if (f) {
        const float* le = lemb + (f == 1 ? 64 : 0);  // 1->label_emb[1], 2->label_emb[0]
        float4 lv = *(const float4*)(le + c4);
        v.x += lv.x; v.y += lv.y; v.z += lv.z; v.w += lv.w;
    }
    *(float4*)(xt + (size_t)row * 64 + c4) = v;
}

// ---- aggregation over 64-dim rows: one wave per node, unroll x8 ----
template <bool BIAS_SILU>
__global__ __launch_bounds__(256) void agg64_kernel(const float* __restrict__ xw,
                                                    const int* __restrict__ rowstart,
                                                    const int2* __restrict__ cs,
                                                    const float* __restrict__ dinv,
                                                    const float* __restrict__ bias,
                                                    float* __restrict__ y, int n) {
    int wid = (int)(((size_t)blockIdx.x * 256 + threadIdx.x) >> 6);
    int lane = threadIdx.x & 63;
    if (wid >= n) return;
    float di = dinv[wid];
    int s = rowstart[wid], e1 = rowstart[wid + 1];
    float a0 = 0.f, a1 = 0.f, a2 = 0.f, a3 = 0.f;
    float a4 = 0.f, a5 = 0.f, a6 = 0.f, a7 = 0.f;
    int e = s;
    for (; e + 8 <= e1; e += 8) {
        int2 c0 = cs[e], c1 = cs[e + 1], c2 = cs[e + 2], c3 = cs[e + 3];
        int2 c4 = cs[e + 4], c5 = cs[e + 5], c6 = cs[e + 6], c7 = cs[e + 7];
        float v0 = xw[(size_t)c0.x * 64 + lane];
        float v1 = xw[(size_t)c1.x * 64 + lane];
        float v2 = xw[(size_t)c2.x * 64 + lane];
        float v3 = xw[(size_t)c3.x * 64 + lane];
        float v4 = xw[(size_t)c4.x * 64 + lane];
        float v5 = xw[(size_t)c5.x * 64 + lane];
        float v6 = xw[(size_t)c6.x * 64 + lane];
        float v7 = xw[(size_t)c7.x * 64 + lane];
        a0 = fmaf(v0, __int_as_float(c0.y) * di, a0);
        a1 = fmaf(v1, __int_as_float(c1.y) * di, a1);
        a2 = fmaf(v2, __int_as_float(c2.y) * di, a2);
        a3 = fmaf(v3, __int_as_float(c3.y) * di, a3);
        a4 = fmaf(v4, __int_as_float(c4.y) * di, a4);
        a5 = fmaf(v5, __int_as_float(c5.y) * di, a5);
        a6 = fmaf(v6, __int_as_float(c6.y) * di, a6);
        a7 = fmaf(v7, __int_as_float(c7.y) * di, a7);
    }
    for (; e + 4 <= e1; e += 4) {
        int2 c0 = cs[e], c1 = cs[e + 1], c2 = cs[e + 2], c3 = cs[e + 3];
        float v0 = xw[(size_t)c0.x * 64 + lane];
        float v1 = xw[(size_t)c1.x * 64 + lane];
        float v2 = xw[(size_t)c2.x * 64 + lane];
        float v3 = xw[(size_t)c3.x * 64 + lane];
        a0 = fmaf(v0, __int_as_float(c0.y) * di, a0);
        a1 = fmaf(v1, __int_as_float(c1.y) * di, a1);
        a2 = fmaf(v2, __int_as_float(c2.y) * di, a2);
        a3 = fmaf(v3, __int_as_float(c3.y) * di, a3);
    }
    for (; e < e1; ++e) {
        int2 c = cs[e];
        a0 = fmaf(xw[(size_t)c.x * 64 + lane], __int_as_float(c.y) * di, a0);
    }
    float acc = ((a0 + a1) + (a2 + a3)) + ((a4 + a5) + (a6 + a7));
    acc = fmaf(xw[(size_t)wid * 64 + lane], di * di, acc);
    if (BIAS_SILU) {
        acc += bias[lane];
        acc = acc / (1.0f + expf(-acc));
    }
    y[(size_t)wid * 64 + lane] = acc;
}

// ---------------------------------------------------------------------------
// Tiled GEMM: y[n][M] = sum over NQ 64-wide k-quarters of xq @ wq (+bias,silu)
// Block: 256 threads, 128-row x M tile. X quarter (128x64) and W quarter
// (64xM) staged in LDS. Thread: 4 rows x M/8 cols.
// NQ==1: xa stride 64. NQ==2: xa stride 128, quarters k=0,64.
// NQ==4: xa,xb stride 128; quarters 0,1 from xa; 2,3 from xb (concat gemm).
// W is [NQ*64][M] row-major (quarter q at rows q*64..q*64+63).
// MODE: 0 plain, 1 = +bias +SiLU.
// ---------------------------------------------------------------------------
template <int M, int NQ, int MODE>
__global__ __launch_bounds__(256) void gemm_tiled_kernel(const float* __restrict__ xa,
                                                         const float* __restrict__ xb,
                                                         const float* __restrict__ w,
                                                         const float* __restrict__ bias,
                                                         float* __restrict__ y, int n) {
    constexpr int XSTRIDE = (NQ == 1) ? 64 : 128;
    constexpr int CPT = M / 8;           // cols per thread
    __shared__ float xl[128 * 65];       // +1 pad: 4-way max bank aliasing
    __shared__ float wl[64 * M];
    const int t = threadIdx.x;
    const int rg = t & 31;               // row group (x4 rows)
    const int cg = t >> 5;               // col group (x CPT cols)
    const int row0 = blockIdx.x * 128;

    float acc[4][CPT];
#pragma unroll
    for (int i = 0; i < 4; ++i)
#pragma unroll
        for (int j = 0; j < CPT; ++j) acc[i][j] = 0.f;

#pragma unroll
    for (int q = 0; q < NQ; ++q) {
        const float* xs = (NQ == 4 && q >= 2) ? xb : xa;
        const int koff = (NQ == 1) ? 0 : (q & 1) * 64;
        if (q) __syncthreads();          // protect previous quarter's reads
        // stage X: 128 rows x 64 floats (2048 float4, 8 per thread)
#pragma unroll
        for (int i = 0; i < 8; ++i) {
            int fid = i * 256 + t;
            int r = fid >> 4;
            int c4 = (fid & 15) * 4;
            int gr = row0 + r;
            float4 v = make_float4(0.f, 0.f, 0.f, 0.f);
            if (gr < n) v = *(const float4*)(xs + (size_t)gr * XSTRIDE + koff + c4);
            float* d = &xl[r * 65 + c4];
            d[0] = v.x; d[1] = v.y; d[2] = v.z; d[3] = v.w;
        }
        // stage W quarter: 64 x M floats
        constexpr int WF4 = 64 * M / 4 / 256;
#pragma unroll
        for (int i = 0; i < WF4; ++i) {
            int fid = i * 256 + t;
            *(float4*)(&wl[fid * 4]) = *(const float4*)(w + (size_t)q * 64 * M + fid * 4);
        }
        __syncthreads();
        // compute this quarter
        const float* xr0 = &xl[(rg * 4 + 0) * 65];
        const float* xr1 = &xl[(rg * 4 + 1) * 65];
        const float* xr2 = &xl[(rg * 4 + 2) * 65];
        const float* xr3 = &xl[(rg * 4 + 3) * 65];
        const float* wc = &wl[cg * CPT];
#pragma unroll 8
        for (int k = 0; k < 64; ++k) {
            float x0 = xr0[k], x1 = xr1[k], x2 = xr2[k], x3 = xr3[k];
            const float* wr = wc + k * M;
#pragma unroll
            for (int j = 0; j < CPT; ++j) {
                float wv = wr[j];
                acc[0][j] = fmaf(x0, wv, acc[0][j]);
                acc[1][j] = fmaf(x1, wv, acc[1][j]);
                acc[2][j] = fmaf(x2, wv, acc[2][j]);
                acc[3][j] = fmaf(x3, wv, acc[3][j]);
            }
        }
    }

    float bb[CPT];
    if (MODE == 1) {
#pragma unroll
        for (int j = 0; j < CPT; ++j) bb[j] = bias[cg * CPT + j];
    }
#pragma unroll
    for (int i = 0; i < 4; ++i) {
        int row = row0 + rg * 4 + i;
        if (row >= n) break;
        float* yr = y + (size_t)row * M + cg * CPT;
#pragma unroll
        for (int j = 0; j < CPT; ++j) {
            float v = acc[i][j];
            if (MODE == 1) { v += bb[j]; v = v / (1.0f + expf(-v)); }
            yr[j] = v;
        }
    }
}

extern "C" void kernel_launch(void* const* d_in, const int* in_sizes, int n_in,
                              void* d_out, int out_size, void* d_ws, size_t ws_size,
                              hipStream_t stream) {
    const float* noise_x = (const float*)d_in[0];
    const int*   edge    = (const int*)d_in[1];
    const int*   tptr    = (const int*)d_in[2];
    const int*   anm     = (const int*)d_in[3];
    const int*   nrm     = (const int*)d_in[4];
    const float* tw1     = (const float*)d_in[5];
    const float* tb1     = (const float*)d_in[6];
    const float* tw2     = (const float*)d_in[7];
    const float* tb2     = (const float*)d_in[8];
    const float* lemb    = (const float*)d_in[9];
    const float* w0      = (const float*)d_in[10];
    const float* b0      = (const float*)d_in[11];
    const float* w1      = (const float*)d_in[12];
    const float* b1      = (const float*)d_in[13];
    const float* w2      = (const float*)d_in[14];
    const float* b2      = (const float*)d_in[15];
    const float* w3      = (const float*)d_in[16];
    const float* b3      = (const float*)d_in[17];

    const int N = in_sizes[0] / 64;
    const int E = in_sizes[1] / 2;
    const int na = in_sizes[3];
    const int nn = in_sizes[4];
    float* out = (float*)d_out;

    // workspace carve-out (256B aligned)
    char* ws = (char*)d_ws;
    size_t o = 0;
    auto carve = [&](size_t bytes) -> char* {
        char* p = ws + o;
        o += (bytes + 255) & ~(size_t)255;
        return p;
    };
    int*   deg      = (int*)carve((size_t)N * 4);
    int*   flag     = (int*)carve((size_t)N * 4);
    int*   rowstart = (int*)carve((size_t)(N + 1) * 4);
    int*   writepos = (int*)carve((size_t)N * 4);
    int*   blocksum = (int*)carve(4096);
    int2*  cs       = (int2*)carve((size_t)E * 8);
    float* dinv     = (float*)carve((size_t)N * 4);
    float* temb     = (float*)carve(256);
    float* bufP     = (float*)carve((size_t)N * 64 * 4);   // x_t -> xw1 -> aggH1 -> z3
    float* bufQ     = (float*)carve((size_t)N * 64 * 4);   // aggX -> h1
    float* bufR     = (float*)carve((size_t)N * 128 * 4);  // h0 (live to end)
    float* bufS     = (float*)carve((size_t)N * 128 * 4);  // h2

    const int nblkN = (N + 255) / 256;
    const int nblkE = (E + 255) / 256;
    const int nb = (N + 1023) / 1024;
    const int nmax = na > nn ? na : nn;
    const int aggBlk = (N + 3) / 4;          // 4 waves (nodes) per 256-thread block
    const int gemmBlk = (N + 127) / 128;     // 128-row tiles

    zero_kernel<<<nblkN, 256, 0, stream>>>(deg, flag, N);
    count_deg_kernel<<<nblkE, 256, 0, stream>>>(edge, deg, E);
    flags_kernel<<<(nmax + 255) / 256, 256, 0, stream>>>(anm, na, nrm, nn, flag);
    dinv_kernel<<<nblkN, 256, 0, stream>>>(deg, dinv, N);
    scan1_kernel<<<nb, 256, 0, stream>>>(deg, rowstart, blocksum, N);
    scan2_kernel<<<1, 64, 0, stream>>>(blocksum, nb);
    scan3_kernel<<<nblkN, 256, 0, stream>>>(rowstart, blocksum, writepos, N, E);
    fill_csr_kernel<<<nblkE, 256, 0, stream>>>(edge, writepos, cs, dinv, E);
    temb_kernel<<<1, 64, 0, stream>>>(tptr, tw1, tb1, tw2, tb2, temb);
    xt_kernel<<<((size_t)N * 16 + 255) / 256, 256, 0, stream>>>(noise_x, temb, lemb, flag, bufP, N);

    // conv0: aggX = agg(x_t); h0 = silu(aggX @ w0 + b0)
    agg64_kernel<false><<<aggBlk, 256, 0, stream>>>(bufP, rowstart, cs, dinv, nullptr, bufQ, N);
    gemm_tiled_kernel<128, 1, 1><<<gemmBlk, 256, 0, stream>>>(bufQ, nullptr, w0, b0, bufR, N);
    // conv1: xw1 = h0 @ w1; h1 = silu(agg(xw1) + b1)
    gemm_tiled_kernel<64, 2, 0><<<gemmBlk, 256, 0, stream>>>(bufR, nullptr, w1, nullptr, bufP, N);
    agg64_kernel<true><<<aggBlk, 256, 0, stream>>>(bufP, rowstart, cs, dinv, b1, bufQ, N);
    // conv2: aggH1 = agg(h1); h2 = silu(aggH1 @ w2 + b2)
    agg64_kernel<false><<<aggBlk, 256, 0, stream>>>(bufQ, rowstart, cs, dinv, nullptr, bufP, N);
    gemm_tiled_kernel<128, 1, 1><<<gemmBlk, 256, 0, stream>>>(bufP, nullptr, w2, b2, bufS, N);
    // conv3: z3 = h2 @ w3[0:128] + h0 @ w3[128:256]; out = silu(agg(z3) + b3)
    gemm_tiled_kernel<64, 4, 0><<<gemmBlk, 256, 0, stream>>>(bufS, bufR, w3, nullptr, bufP, N);
    agg64_kernel<true><<<aggBlk, 256, 0, stream>>>(bufP, rowstart, cs, dinv, b3, out, N);
}